// Round 2
// baseline (74.614 us; speedup 1.0000x reference)
//
#include <hip/hip_runtime.h>

#define BATCH   4
#define NCUR    8192
#define NSUR    24576
#define NPTS    (NCUR + NSUR)          // 32768 points per batch
#define NPATCH  64                     // B * 16
#define GS      18
#define LS      36
#define GVOL    (GS*GS*GS)             // 5832
#define LVOL    (LS*LS*LS)             // 46656
#define GOUT_TOTAL (NPATCH*2*GVOL)     // 746496
#define WINNER_INT4 (BATCH*128*128*128/4)   // 2,097,152 int4 slots

// ---------------------------------------------------------------------------
// Kernel 0: fill winner grid with -1 (replaces slow rocclr fillBuffer)
// ---------------------------------------------------------------------------
__global__ __launch_bounds__(256)
void fill_winner_kernel(int4* __restrict__ w)
{
    int idx = blockIdx.x * 256 + threadIdx.x;
    const int4 m1 = make_int4(-1, -1, -1, -1);
    for (int i = idx; i < WINNER_INT4; i += 256 * 1024)
        w[i] = m1;
}

// ---------------------------------------------------------------------------
// Kernel 1: per-point MLP (3 -> 128 -> 16), 2 points/thread, float4 weight
// reads; scatter winner index via atomicMax (last-write-wins == max n wins).
// ---------------------------------------------------------------------------
__global__ __launch_bounds__(256)
void mlp_scatter_kernel(const float* __restrict__ curves,
                        const float* __restrict__ surfaces,
                        const float* __restrict__ W1,
                        const float* __restrict__ b1,
                        const float* __restrict__ W2,
                        const float* __restrict__ b2,
                        int*   __restrict__ winner,   // (B,128,128,128), pre-filled -1
                        float* __restrict__ feat)     // (B,NPTS,16)
{
    __shared__ float4 sW1p[128];   // xyz = W1 row, w = b1
    __shared__ float4 sW2v[512];   // (16,128) as float4
    __shared__ float  sb2[16];
    int t = threadIdx.x;
    if (t < 128) sW1p[t] = make_float4(W1[3*t], W1[3*t+1], W1[3*t+2], b1[t]);
    for (int u = t; u < 512; u += 256) sW2v[u] = ((const float4*)W2)[u];
    if (t < 16) sb2[t] = b2[t];
    __syncthreads();

    int pi = blockIdx.x * 256 + t;       // pair index
    int g0 = pi * 2;                     // first global point id
    if (g0 >= BATCH * NPTS) return;
    int b = g0 / NPTS;
    int n = g0 - b * NPTS;               // even; pair never straddles sources

    const float* src;
    if (n < NCUR) src = curves   + ((size_t)b * NCUR + n) * 3;
    else          src = surfaces + ((size_t)b * NSUR + (n - NCUR)) * 3;
    float2 p01 = ((const float2*)src)[0];
    float2 p23 = ((const float2*)src)[1];
    float2 p45 = ((const float2*)src)[2];
    float ax = p01.x, ay = p01.y, az = p23.x;
    float bx = p23.y, by = p45.x, bz = p45.y;

    float accA[16], accB[16];
    #pragma unroll
    for (int o = 0; o < 16; ++o) { accA[o] = sb2[o]; accB[o] = sb2[o]; }

    #pragma unroll 2
    for (int c0 = 0; c0 < 128; c0 += 4) {
        float hA[4], hB[4];
        #pragma unroll
        for (int cc = 0; cc < 4; ++cc) {
            float4 w = sW1p[c0 + cc];
            hA[cc] = fmaxf(fmaf(az, w.z, fmaf(ay, w.y, fmaf(ax, w.x, w.w))), 0.0f);
            hB[cc] = fmaxf(fmaf(bz, w.z, fmaf(by, w.y, fmaf(bx, w.x, w.w))), 0.0f);
        }
        #pragma unroll
        for (int o = 0; o < 16; ++o) {
            float4 wv = sW2v[o * 32 + (c0 >> 2)];
            accA[o] = fmaf(hA[3], wv.w, fmaf(hA[2], wv.z,
                      fmaf(hA[1], wv.y, fmaf(hA[0], wv.x, accA[o]))));
            accB[o] = fmaf(hB[3], wv.w, fmaf(hB[2], wv.z,
                      fmaf(hB[1], wv.y, fmaf(hB[0], wv.x, accB[o]))));
        }
    }

    float4* foA = (float4*)(feat + (size_t)g0 * 16);
    foA[0] = make_float4(accA[0],  accA[1],  accA[2],  accA[3]);
    foA[1] = make_float4(accA[4],  accA[5],  accA[6],  accA[7]);
    foA[2] = make_float4(accA[8],  accA[9],  accA[10], accA[11]);
    foA[3] = make_float4(accA[12], accA[13], accA[14], accA[15]);
    float4* foB = (float4*)(feat + (size_t)(g0 + 1) * 16);
    foB[0] = make_float4(accB[0],  accB[1],  accB[2],  accB[3]);
    foB[1] = make_float4(accB[4],  accB[5],  accB[6],  accB[7]);
    foB[2] = make_float4(accB[8],  accB[9],  accB[10], accB[11]);
    foB[3] = make_float4(accB[12], accB[13], accB[14], accB[15]);

    // cell index: clip(x*128 + 64.5, 0, 127), truncate; non-fused to match numpy
    {
        float cx = fminf(fmaxf(__fadd_rn(__fmul_rn(ax, 128.0f), 64.5f), 0.0f), 127.0f);
        float cy = fminf(fmaxf(__fadd_rn(__fmul_rn(ay, 128.0f), 64.5f), 0.0f), 127.0f);
        float cz = fminf(fmaxf(__fadd_rn(__fmul_rn(az, 128.0f), 64.5f), 0.0f), 127.0f);
        atomicMax(winner + ((((size_t)b*128 + (int)cx)*128 + (int)cy)*128 + (int)cz), n);
    }
    {
        float cx = fminf(fmaxf(__fadd_rn(__fmul_rn(bx, 128.0f), 64.5f), 0.0f), 127.0f);
        float cy = fminf(fmaxf(__fadd_rn(__fmul_rn(by, 128.0f), 64.5f), 0.0f), 127.0f);
        float cz = fminf(fmaxf(__fadd_rn(__fmul_rn(bz, 128.0f), 64.5f), 0.0f), 127.0f);
        atomicMax(winner + ((((size_t)b*128 + (int)cx)*128 + (int)cy)*128 + (int)cz), n + 1);
    }
}

// ---------------------------------------------------------------------------
// Kernel 2: global patches (64, 2, 18,18,18) from occ (B,2,64,64,64), pad 1
// ---------------------------------------------------------------------------
__global__ __launch_bounds__(256)
void global_patch_kernel(const float* __restrict__ occ,
                         const int*   __restrict__ indices,
                         float* __restrict__ out)
{
    int gid = blockIdx.x * 256 + threadIdx.x;
    if (gid >= GOUT_TOTAL) return;
    int z = gid % 18;
    int y = (gid / 18) % 18;
    int x = (gid / 324) % 18;
    int c = (gid / GVOL) & 1;
    int q = gid / (2 * GVOL);

    int b = q >> 4;
    int p = indices[q];
    int i = p >> 4, j = (p >> 2) & 3, k = p & 3;

    int X = i*16 + x - 1;
    int Y = j*16 + y - 1;
    int Z = k*16 + z - 1;
    float v = 0.0f;
    if ((unsigned)X < 64u && (unsigned)Y < 64u && (unsigned)Z < 64u)
        v = occ[((((size_t)b*2 + c)*64 + X)*64 + Y)*64 + Z];
    out[gid] = v;
}

// ---------------------------------------------------------------------------
// Kernel 3: local patches (64, 16, 36,36,36). One thread per 4 consecutive z;
// 16 float4 stores per thread. One winner read per z serves all 16 channels.
// ---------------------------------------------------------------------------
#define LROWS (LS*LS*(LS/4))   // 11664 thread-slots per patch
__global__ __launch_bounds__(256)
void local_patch_kernel(const int*   __restrict__ winner,
                        const float* __restrict__ feat,
                        const int*   __restrict__ indices,
                        float* __restrict__ out)   // local section base
{
    int gid = blockIdx.x * 256 + threadIdx.x;
    if (gid >= NPATCH * LROWS) return;
    int q  = gid / LROWS;
    int r  = gid - q * LROWS;
    int x  = r / 324;
    int r2 = r - x * 324;
    int y  = r2 / 9;
    int zi = r2 - y * 9;                // z = zi*4 .. zi*4+3

    int b = q >> 4;
    int p = indices[q];
    int i = p >> 4, j = (p >> 2) & 3, k = p & 3;

    int X  = i*32 + x - 2;
    int Y  = j*32 + y - 2;
    int Zb = k*32 + zi*4 - 2;
    bool xyok = ((unsigned)X < 128u) & ((unsigned)Y < 128u);
    const int* wrow = winner + (((size_t)b*128 + X)*128 + Y)*128;

    int w[4];
    #pragma unroll
    for (int dz = 0; dz < 4; ++dz) {
        int Z = Zb + dz;
        w[dz] = (xyok && (unsigned)Z < 128u) ? wrow[Z] : -1;
    }

    float4 vc[16];
    #pragma unroll
    for (int c = 0; c < 16; ++c) vc[c] = make_float4(0.f, 0.f, 0.f, 0.f);

    #pragma unroll
    for (int dz = 0; dz < 4; ++dz) {
        if (w[dz] >= 0) {
            const float4* f = (const float4*)(feat + ((size_t)b*NPTS + w[dz])*16);
            float4 a0 = f[0], a1 = f[1], a2 = f[2], a3 = f[3];
            float fv[16] = {a0.x,a0.y,a0.z,a0.w, a1.x,a1.y,a1.z,a1.w,
                            a2.x,a2.y,a2.z,a2.w, a3.x,a3.y,a3.z,a3.w};
            #pragma unroll
            for (int c = 0; c < 16; ++c) {
                if (dz == 0) vc[c].x = fv[c];
                if (dz == 1) vc[c].y = fv[c];
                if (dz == 2) vc[c].z = fv[c];
                if (dz == 3) vc[c].w = fv[c];
            }
        }
    }

    size_t base = (size_t)q * 16 * LVOL + (size_t)x * 1296 + y * 36 + zi * 4;
    #pragma unroll
    for (int c = 0; c < 16; ++c)
        *(float4*)(out + base + (size_t)c * LVOL) = vc[c];
}

// ---------------------------------------------------------------------------
extern "C" void kernel_launch(void* const* d_in, const int* in_sizes, int n_in,
                              void* d_out, int out_size, void* d_ws, size_t ws_size,
                              hipStream_t stream)
{
    const float* curves   = (const float*)d_in[0];
    const float* surfaces = (const float*)d_in[1];
    const float* occ      = (const float*)d_in[2];
    const int*   indices  = (const int*)  d_in[3];
    const float* W1       = (const float*)d_in[4];
    const float* b1       = (const float*)d_in[5];
    const float* W2       = (const float*)d_in[6];
    const float* b2       = (const float*)d_in[7];

    const size_t winner_bytes = (size_t)BATCH * 128 * 128 * 128 * sizeof(int); // 33.5 MB
    int*   winner = (int*)d_ws;
    float* feat   = (float*)((char*)d_ws + winner_bytes);                      // 8.4 MB

    fill_winner_kernel<<<1024, 256, 0, stream>>>((int4*)winner);

    mlp_scatter_kernel<<<(BATCH*NPTS/2 + 255)/256, 256, 0, stream>>>(
        curves, surfaces, W1, b1, W2, b2, winner, feat);

    global_patch_kernel<<<(GOUT_TOTAL + 255)/256, 256, 0, stream>>>(
        occ, indices, (float*)d_out);

    local_patch_kernel<<<(NPATCH*LROWS + 255)/256, 256, 0, stream>>>(
        winner, feat, indices, (float*)d_out + GOUT_TOTAL);
}